// Round 14
// baseline (26.653 us; speedup 1.0000x reference)
//
#include <hip/hip_runtime.h>

// SpinConvSq2d via MFMA (bf16). Round 14: phase-pipelined persistent blocks.
//  R8-R13 all land 23-25us because grid==resident capacity -> all blocks march
//  stage->loop->epi in lockstep; nothing overlaps (R13's 4 blocks/CU proved
//  co-residency alone doesn't help). This round: 512 persistent blocks, each
//  processes its column's two 32px y-halves with double-buffered 23KB tiles:
//   issue stage(buf0)+stage(buf1) -> vmcnt(5)+s_barrier (counted, never 0)
//   -> loop0 -> epi0 -> store0 (async) -> loop1 (store0+stage1 hidden) ->
//   epi1 -> store1.
//  Compute = R13's 4-role structure (S/V/T/U), refchecked, absmax 0.0156.
// out0   = A0*(SH0*S000 + CG110*dot(s,V));  s = SH1*spin
// out1_i = A1*(s_i*S011 + SH0*T_i + CG111*cross(U,s)_i)

typedef __attribute__((ext_vector_type(8))) short short8;
typedef __attribute__((ext_vector_type(16))) float f32x16;
typedef __attribute__((ext_vector_type(4))) float float4v;

typedef __attribute__((address_space(3))) unsigned char lds_u8_t;
typedef const __attribute__((address_space(1))) unsigned char g_u8_t;

#define FEATT_BYTES (8u * 64u * 64u * 64u * 2u)   // 4 MB bf16 featT
#define BT_OFFSET   FEATT_BYTES                    // weight blob: 64000*2 B

#define MFMA32(A, B, C) __builtin_amdgcn_mfma_f32_32x32x16_bf16(A, B, C, 0, 0, 0)

__device__ __forceinline__ unsigned short f2bf(float f) {
    unsigned int u = __float_as_uint(f);
    return (unsigned short)((u + 0x7FFFu + ((u >> 16) & 1u)) >> 16);  // RNE
}

// ---------------- prep: featT [col][slot][y] bf16 + weight blob ----------------
__global__ __launch_bounds__(256) void prep_kernel(
    const float* __restrict__ feat,
    const float* __restrict__ W000, const float* __restrict__ W110,
    const float* __restrict__ W011, const float* __restrict__ W101,
    const float* __restrict__ W111,
    unsigned char* __restrict__ ws)
{
    int tid = threadIdx.x;
    int b = blockIdx.x;
    if (b < 512) {
        __shared__ float sf[64][68];          // 68-pad spreads banks
        size_t base = (size_t)b * 4096;       // floats (= shorts per column)
        #pragma unroll
        for (int i = 0; i < 4; ++i) {
            int e = tid + i * 256;            // float4 index 0..1023
            float4v v = *(const float4v*)(feat + base + (size_t)e * 4);
            int px = e >> 4;
            int c  = (e & 15) * 4;
            sf[px][c + 0] = v[0]; sf[px][c + 1] = v[1];
            sf[px][c + 2] = v[2]; sf[px][c + 3] = v[3];
        }
        __syncthreads();
        unsigned short* dst = (unsigned short*)ws + base;
        #pragma unroll
        for (int i = 0; i < 2; ++i) {
            int t = tid + i * 256;            // 0..511: s*64 + px
            int s = t >> 6, px = t & 63;
            short8 o;
            #pragma unroll
            for (int j = 0; j < 8; ++j) {
                int chp = s * 8 + j;
                int c = (chp < 16) ? chp : (16 + 3 * ((chp - 16) & 15) + ((chp - 16) >> 4));
                o[j] = (short)f2bf(sf[px][c]);
            }
            *(short8*)(dst + s * 512 + px * 8) = o;   // [slot][y] within column
        }
    } else {
        int t = (b - 512) * 256 + tid;        // 0..4095, need <4000
        if (t >= 4000) return;
        int a = t / 160, colv = t - a * 160;
        int arr = colv >> 5, w = colv & 31;
        const float* Wp = (arr == 0) ? W000 : (arr == 1) ? W011
                        : (arr == 2) ? W110 : (arr == 3) ? W101 : W111;
        unsigned short tmp[16];
        #pragma unroll
        for (int k = 0; k < 16; ++k) tmp[k] = f2bf(Wp[a * 512 + k * 32 + w]);
        unsigned short* d = (unsigned short*)(ws + BT_OFFSET) + (size_t)t * 16;
        *(short8*)(d)     = *(short8*)(tmp);
        *(short8*)(d + 8) = *(short8*)(tmp + 8);
    }
}

// ---------------- main MFMA kernel (persistent 2-tile pipelined blocks) ------
// Tile th (y0 = th*32): LDS [dx 0..4][slot 0..7][l 0..35] x 16B, l <-> y =
// (y0-2+l)&63; chunk e = (dx*8+slot)*36 + l at byte e*16 (linear, 23040B).
__global__ __launch_bounds__(256, 3) void spinconv_mfma_kernel(
    const unsigned char* __restrict__ featT8,
    const unsigned char* __restrict__ bt,
    const float* __restrict__ spin,
    float* __restrict__ out)
{
    const float SH0f   = 0.28209479177387814f;
    const float CG110f = 0.5773502691896258f;
    const float CG111f = 0.7071067811865476f;
    const float A0f    = 0.035355339059327376f;
    const float A1f    = 0.028867513459481287f;

    __shared__ __align__(16) unsigned char fl[2][23040];   // double-buffered tiles
    __shared__ float s_lds[192];                           // SH1*spin, both halves

    int tid = threadIdx.x;
    int b = blockIdx.x;
    int column = ((b & 7) << 6) + (b >> 3);   // XCD-aware: n*64 + x
    int x = column & 63;
    int colbase = column - x;

    int lane = tid & 63;
    int wv4 = tid >> 6;                       // 0..3

    // spin -> registers now (LDS write deferred to epilogue; avoids an early
    // compiler vmcnt drain that would kill the async pipeline)
    float spinval = 0.f;
    if (tid < 192) spinval = 0.4886025119029199f * spin[(size_t)column * 192 + tid];

    // ---- issue BOTH tiles' staging up-front (async, linear LDS dest) ----
    #pragma unroll
    for (int th = 0; th < 2; ++th) {
        #pragma unroll
        for (int i = 0; i < 6; ++i) {
            int e = tid + (i << 8);            // chunk id 0..1535 (<1440 valid)
            if (e < 1440) {
                int g = e / 36;
                int l = e - g * 36;
                int dx = g >> 3, slot = g & 7;
                int X = (x + dx + 62) & 63;
                int y = ((th << 5) + l + 62) & 63;
                const unsigned char* src = featT8
                    + (size_t)(colbase + X) * 8192 + slot * 1024 + y * 16;
                __builtin_amdgcn_global_load_lds((g_u8_t*)src,
                    (lds_u8_t*)(fl[th] + ((i << 8) + (tid & ~63)) * 16), 16, 0, 0);
            }
        }
    }
    // tile0 ready: counted wait (tile1's loads stay in flight), raw barrier.
    // Per-thread issue counts: tid<160: 6+6 (+1 spin), 160..191: 5+5(+1),
    // 192..255: 5+5 -> vmcnt(5) covers tile0 for every class.
    asm volatile("s_waitcnt vmcnt(5)" ::: "memory");
    __builtin_amdgcn_sched_barrier(0);
    __builtin_amdgcn_s_barrier();

    int role = (wv4 + (b & 3)) & 3;        // rotate roles across SIMDs
    int col = lane & 31;                   // N-col (w) and A-row (pixel in tile)
    int khalf = lane >> 5;                 // K-half select
    const unsigned char* bbase = bt + col * 32 + khalf * 16;

    f32x16 zz;
    #pragma unroll
    for (int i = 0; i < 16; ++i) zz[i] = 0.f;

    #pragma unroll
    for (int th = 0; th < 2; ++th) {
        const unsigned char* ft = fl[th];
        // role S(0): ac0=S000 ac1=S011 | V(1)/T(2)/U(3): ac0..2 per component
        f32x16 ac0 = zz, ac1 = zz, ac2 = zz;

        if (role == 0) {
            short8 B0c, B1c, B0n, B1n, Axc, Axn;
            auto loadB = [&](int a, short8& b0, short8& b1) {
                const unsigned char* p = bbase + a * 5120;
                b0 = *(const short8*)(p);            // W000
                b1 = *(const short8*)(p + 1024);     // W011
            };
            auto loadA = [&](int a, short8& ax) {
                int ix = a / 5;
                int iy = a - ix * 5;
                ax = *(const short8*)(ft + ix * 4608 + khalf * 576 + (col + iy) * 16);
            };
            loadB(0, B0c, B1c);
            loadA(0, Axc);
            #pragma unroll
            for (int ap = 0; ap < 25; ap += 2) {
                if (ap + 1 < 25) { loadB(ap + 1, B0n, B1n); loadA(ap + 1, Axn); }
                __builtin_amdgcn_s_setprio(1);
                ac0 = MFMA32(Axc, B0c, ac0);
                ac1 = MFMA32(Axc, B1c, ac1);
                __builtin_amdgcn_s_setprio(0);
                if (ap + 1 < 25) {
                    if (ap + 2 < 25) { loadB(ap + 2, B0c, B1c); loadA(ap + 2, Axc); }
                    __builtin_amdgcn_s_setprio(1);
                    ac0 = MFMA32(Axn, B0n, ac0);
                    ac1 = MFMA32(Axn, B1n, ac1);
                    __builtin_amdgcn_s_setprio(0);
                }
            }
        } else {
            const int matoff = (role + 1) << 10;   // V->2048 T->3072 U->4096
            short8 Bc, Bn, C0c, C1c, C2c, C0n, C1n, C2n;
            auto loadB = [&](int a, short8& bb) {
                bb = *(const short8*)(bbase + a * 5120 + matoff);
            };
            auto loadA = [&](int a, short8& c0, short8& c1, short8& c2) {
                int ix = a / 5;
                int iy = a - ix * 5;
                const unsigned char* ab = ft + ix * 4608 + (col + iy) * 16;
                c0 = *(const short8*)(ab + (2 + khalf) * 576);
                c1 = *(const short8*)(ab + (4 + khalf) * 576);
                c2 = *(const short8*)(ab + (6 + khalf) * 576);
            };
            loadB(0, Bc);
            loadA(0, C0c, C1c, C2c);
            #pragma unroll
            for (int ap = 0; ap < 25; ap += 2) {
                if (ap + 1 < 25) { loadB(ap + 1, Bn); loadA(ap + 1, C0n, C1n, C2n); }
                __builtin_amdgcn_s_setprio(1);
                ac0 = MFMA32(C0c, Bc, ac0);
                ac1 = MFMA32(C1c, Bc, ac1);
                ac2 = MFMA32(C2c, Bc, ac2);
                __builtin_amdgcn_s_setprio(0);
                if (ap + 1 < 25) {
                    if (ap + 2 < 25) { loadB(ap + 2, Bc); loadA(ap + 2, C0c, C1c, C2c); }
                    __builtin_amdgcn_s_setprio(1);
                    ac0 = MFMA32(C0n, Bn, ac0);
                    ac1 = MFMA32(C1n, Bn, ac1);
                    ac2 = MFMA32(C2n, Bn, ac2);
                    __builtin_amdgcn_s_setprio(0);
                }
            }
        }

        // ---- epilogue for this tile: rowbuf reuses the tile's own (dead) buf ----
        if (th == 0 && tid < 192) s_lds[tid] = spinval;   // spin load long done
        __syncthreads();   // tile ready for reuse; also makes buf1 ready (th==0)

        float* rowbuf = (float*)fl[th];            // [32][128] floats
        const float* sp = s_lds + th * 96;

        if (role == 0) {
            #pragma unroll
            for (int r = 0; r < 16; ++r) {
                int yl = (r & 3) + ((r >> 2) << 3) + (khalf << 2);
                float s0 = sp[yl * 3 + 0];
                float s1 = sp[yl * 3 + 1];
                float s2 = sp[yl * 3 + 2];
                float S000 = ac0[r], S011 = ac1[r];
                float* rb = rowbuf + yl * 128;
                float* rp = rb + 32 + 3 * col;
                rb[col] = A0f * SH0f * S000;
                rp[0] = A1f * s0 * S011;
                rp[1] = A1f * s1 * S011;
                rp[2] = A1f * s2 * S011;
            }
        }
        __syncthreads();
        if (role == 1) {
            #pragma unroll
            for (int r = 0; r < 16; ++r) {
                int yl = (r & 3) + ((r >> 2) << 3) + (khalf << 2);
                float s0 = sp[yl * 3 + 0];
                float s1 = sp[yl * 3 + 1];
                float s2 = sp[yl * 3 + 2];
                rowbuf[yl * 128 + col] +=
                    A0f * CG110f * (s0 * ac0[r] + s1 * ac1[r] + s2 * ac2[r]);
            }
        } else if (role == 2) {
            #pragma unroll
            for (int r = 0; r < 16; ++r) {
                int yl = (r & 3) + ((r >> 2) << 3) + (khalf << 2);
                float* rp = rowbuf + yl * 128 + 32 + 3 * col;
                rp[0] += A1f * SH0f * ac0[r];
                rp[1] += A1f * SH0f * ac1[r];
                rp[2] += A1f * SH0f * ac2[r];
            }
        }
        __syncthreads();
        if (role == 3) {
            #pragma unroll
            for (int r = 0; r < 16; ++r) {
                int yl = (r & 3) + ((r >> 2) << 3) + (khalf << 2);
                float s0 = sp[yl * 3 + 0];
                float s1 = sp[yl * 3 + 1];
                float s2 = sp[yl * 3 + 2];
                float U0 = ac0[r], U1 = ac1[r], U2 = ac2[r];
                float* rp = rowbuf + yl * 128 + 32 + 3 * col;
                rp[0] += A1f * CG111f * (U1 * s2 - U2 * s1);
                rp[1] += A1f * CG111f * (U2 * s0 - U0 * s2);
                rp[2] += A1f * CG111f * (U0 * s1 - U1 * s0);
            }
        }
        __syncthreads();

        // ---- contiguous store (async wrt next tile's loop: no wait needed) ----
        float* ob = out + ((size_t)column * 64 + (th << 5)) * 128;
        #pragma unroll
        for (int i = 0; i < 4; ++i) {
            int e = (tid + (i << 8)) << 2;         // float offset, 16B-aligned
            *(float4v*)(ob + e) = *(const float4v*)(rowbuf + e);
        }
        // NOTE: loop1 reads fl[1] only; rowbuf0 = fl[0] already consumed by the
        // ds_reads above (program order) -> safe to proceed without more syncs.
    }
}

extern "C" void kernel_launch(void* const* d_in, const int* in_sizes, int n_in,
                              void* d_out, int out_size, void* d_ws, size_t ws_size,
                              hipStream_t stream) {
    const float* feat = (const float*)d_in[0];
    const float* spin = (const float*)d_in[1];
    const float* W000 = (const float*)d_in[2];
    const float* W110 = (const float*)d_in[3];
    const float* W011 = (const float*)d_in[4];
    const float* W101 = (const float*)d_in[5];
    const float* W111 = (const float*)d_in[6];
    float* out = (float*)d_out;
    unsigned char* ws = (unsigned char*)d_ws;

    hipLaunchKernelGGL(prep_kernel, dim3(528), dim3(256), 0, stream,
                       feat, W000, W110, W011, W101, W111, ws);
    hipLaunchKernelGGL(spinconv_mfma_kernel, dim3(512), dim3(256), 0, stream,
                       ws, ws + BT_OFFSET, spin, out);
}

// Round 15
// 22.844 us; speedup vs baseline: 1.1667x; 1.1667x over previous
//
#include <hip/hip_runtime.h>

// SpinConvSq2d via MFMA (bf16). Round 15: 32-px staggered blocks + direct
// full-coverage stores.
//  - 128-thr blocks {role0,role1} using R9's proven 5/6-acc partition
//    (VGPR 80): role0: S000,S011,V0-2 (B:W000,W011,W110; reads ax,c0-2);
//    role1: T0-2,U0-2 (B:W101,W111; reads c0-2). Grid 1024, 23KB linear
//    tile (R13 36-row window) -> ~4-5 blocks/CU staggered (stage/epi of one
//    block hides under others' tap loops; R14's forced pipeline regressed).
//  - Epilogue: S011 handoff via 4KB sbuf (1 barrier), then DIRECT stores:
//    out0 = 1 dword/lane (wave covers full 128B px-row), out1 = one 12B
//    contiguous store/lane (wave covers [128,512) of a px fully) -> no
//    partial-sector RMW (R6's inflation was per-dword stride-3 stores).
// out0   = A0*(SH0*S000 + CG110*dot(s,V));  s = SH1*spin
// out1_i = A1*(s_i*S011 + SH0*T_i + CG111*cross(U,s)_i)

typedef __attribute__((ext_vector_type(8))) short short8;
typedef __attribute__((ext_vector_type(16))) float f32x16;
typedef __attribute__((ext_vector_type(4))) float float4v;

typedef __attribute__((address_space(3))) unsigned char lds_u8_t;
typedef const __attribute__((address_space(1))) unsigned char g_u8_t;

#define FEATT_BYTES (8u * 64u * 64u * 64u * 2u)   // 4 MB bf16 featT
#define BT_OFFSET   FEATT_BYTES                    // weight blob: 64000*2 B

#define MFMA32(A, B, C) __builtin_amdgcn_mfma_f32_32x32x16_bf16(A, B, C, 0, 0, 0)

struct F3 { float a, b, c; };

__device__ __forceinline__ unsigned short f2bf(float f) {
    unsigned int u = __float_as_uint(f);
    return (unsigned short)((u + 0x7FFFu + ((u >> 16) & 1u)) >> 16);  // RNE
}

// ---------------- prep: featT [col][slot][y] bf16 + weight blob ----------------
__global__ __launch_bounds__(256) void prep_kernel(
    const float* __restrict__ feat,
    const float* __restrict__ W000, const float* __restrict__ W110,
    const float* __restrict__ W011, const float* __restrict__ W101,
    const float* __restrict__ W111,
    unsigned char* __restrict__ ws)
{
    int tid = threadIdx.x;
    int b = blockIdx.x;
    if (b < 512) {
        __shared__ float sf[64][68];          // 68-pad spreads banks
        size_t base = (size_t)b * 4096;       // floats (= shorts per column)
        #pragma unroll
        for (int i = 0; i < 4; ++i) {
            int e = tid + i * 256;            // float4 index 0..1023
            float4v v = *(const float4v*)(feat + base + (size_t)e * 4);
            int px = e >> 4;
            int c  = (e & 15) * 4;
            sf[px][c + 0] = v[0]; sf[px][c + 1] = v[1];
            sf[px][c + 2] = v[2]; sf[px][c + 3] = v[3];
        }
        __syncthreads();
        unsigned short* dst = (unsigned short*)ws + base;
        #pragma unroll
        for (int i = 0; i < 2; ++i) {
            int t = tid + i * 256;            // 0..511: s*64 + px
            int s = t >> 6, px = t & 63;
            short8 o;
            #pragma unroll
            for (int j = 0; j < 8; ++j) {
                int chp = s * 8 + j;
                int c = (chp < 16) ? chp : (16 + 3 * ((chp - 16) & 15) + ((chp - 16) >> 4));
                o[j] = (short)f2bf(sf[px][c]);
            }
            *(short8*)(dst + s * 512 + px * 8) = o;   // [slot][y] within column
        }
    } else {
        int t = (b - 512) * 256 + tid;        // 0..4095, need <4000
        if (t >= 4000) return;
        int a = t / 160, colv = t - a * 160;
        int arr = colv >> 5, w = colv & 31;
        const float* Wp = (arr == 0) ? W000 : (arr == 1) ? W011
                        : (arr == 2) ? W110 : (arr == 3) ? W101 : W111;
        unsigned short tmp[16];
        #pragma unroll
        for (int k = 0; k < 16; ++k) tmp[k] = f2bf(Wp[a * 512 + k * 32 + w]);
        unsigned short* d = (unsigned short*)(ws + BT_OFFSET) + (size_t)t * 16;
        *(short8*)(d)     = *(short8*)(tmp);
        *(short8*)(d + 8) = *(short8*)(tmp + 8);
    }
}

// ---------------- main MFMA kernel (32-px blocks, 2 role-waves) ----------------
// LDS tile: [dx 0..4][slot 0..7][l 0..35] x 16B, l <-> y = (y0-2+l)&63;
// chunk e = (dx*8+slot)*36 + l at byte e*16 (fully linear, 23040 B).
__global__ __launch_bounds__(128, 3) void spinconv_mfma_kernel(
    const unsigned char* __restrict__ featT8,
    const unsigned char* __restrict__ bt,
    const float* __restrict__ spin,
    float* __restrict__ out)
{
    const float SH0f   = 0.28209479177387814f;
    const float CG110f = 0.5773502691896258f;
    const float CG111f = 0.7071067811865476f;
    const float A0f    = 0.035355339059327376f;
    const float A1f    = 0.028867513459481287f;

    __shared__ __align__(16) unsigned char fl[1440 * 16];   // 23040 B tile
    __shared__ float sbuf[16][64];                          // 4 KB S011 handoff
    __shared__ float s_lds[96];                             // SH1*spin (32 px)

    int tid = threadIdx.x;
    int b = blockIdx.x;
    int L = ((b & 7) << 7) + (b >> 3);     // XCD-aware remap
    int column = L >> 1;                   // n*64 + x
    int x = column & 63;
    int y0 = (L & 1) << 5;                 // y-half base

    int lane = tid & 63;
    int wv = tid >> 6;                     // 0..1

    // ---- async stage: 1440 16B chunks, linear LDS, wrapped per-lane source ----
    #pragma unroll
    for (int i = 0; i < 12; ++i) {
        int e = tid + (i << 7);            // chunk id
        if (e < 1440) {
            int g = e / 36;                // 0..39
            int l = e - g * 36;
            int dx = g >> 3, slot = g & 7;
            int X = (x + dx + 62) & 63;
            int y = (y0 + l + 62) & 63;    // y0 - 2 + l (mod 64)
            const unsigned char* src = featT8
                + (size_t)(column - x + X) * 8192 + slot * 1024 + y * 16;
            __builtin_amdgcn_global_load_lds((g_u8_t*)src,
                (lds_u8_t*)(fl + ((i << 7) + (tid & ~63)) * 16), 16, 0, 0);
        }
    }
    if (tid < 96) {
        s_lds[tid] = 0.4886025119029199f
                   * spin[((size_t)column * 64 + y0) * 3 + tid];
    }
    __syncthreads();

    int role = wv ^ (b & 1);               // mix role->SIMD assignment
    int col = lane & 31;                   // N-col (w) and A-row (pixel in tile)
    int khalf = lane >> 5;                 // K-half select
    const unsigned char* bbase = bt + col * 32 + khalf * 16;

    f32x16 zz;
    #pragma unroll
    for (int i = 0; i < 16; ++i) zz[i] = 0.f;

    // role0: ac0=S000 ac1=S011 ac2=V0 ac3=V1 ac4=V2
    // role1: ac0=T0 ac1=T1 ac2=T2 ac3=U0 ac4=U1 ac5=U2 (ac5 only role1)
    f32x16 ac0 = zz, ac1 = zz, ac2 = zz, ac3 = zz, ac4 = zz, ac5 = zz;

    if (role == 0) {
        short8 B0c, B1c, B2c, B0n, B1n, B2n;
        short8 Axc, C0c, C1c, C2c, Axn, C0n, C1n, C2n;
        auto loadB = [&](int a, short8& b0, short8& b1, short8& b2) {
            const unsigned char* p = bbase + a * 5120;
            b0 = *(const short8*)(p);            // W000
            b1 = *(const short8*)(p + 1024);     // W011
            b2 = *(const short8*)(p + 2048);     // W110
        };
        auto loadA = [&](int a, short8& ax, short8& c0, short8& c1, short8& c2) {
            int ix = a / 5;
            int iy = a - ix * 5;
            const unsigned char* ab = fl + ix * 4608 + (col + iy) * 16;
            ax = *(const short8*)(ab + khalf * 576);
            c0 = *(const short8*)(ab + (2 + khalf) * 576);
            c1 = *(const short8*)(ab + (4 + khalf) * 576);
            c2 = *(const short8*)(ab + (6 + khalf) * 576);
        };
        loadB(0, B0c, B1c, B2c);
        loadA(0, Axc, C0c, C1c, C2c);
        #pragma unroll
        for (int ap = 0; ap < 25; ap += 2) {
            if (ap + 1 < 25) { loadB(ap + 1, B0n, B1n, B2n); loadA(ap + 1, Axn, C0n, C1n, C2n); }
            __builtin_amdgcn_s_setprio(1);
            ac0 = MFMA32(Axc, B0c, ac0);
            ac1 = MFMA32(Axc, B1c, ac1);
            ac2 = MFMA32(C0c, B2c, ac2);
            ac3 = MFMA32(C1c, B2c, ac3);
            ac4 = MFMA32(C2c, B2c, ac4);
            __builtin_amdgcn_s_setprio(0);
            if (ap + 1 < 25) {
                if (ap + 2 < 25) { loadB(ap + 2, B0c, B1c, B2c); loadA(ap + 2, Axc, C0c, C1c, C2c); }
                __builtin_amdgcn_s_setprio(1);
                ac0 = MFMA32(Axn, B0n, ac0);
                ac1 = MFMA32(Axn, B1n, ac1);
                ac2 = MFMA32(C0n, B2n, ac2);
                ac3 = MFMA32(C1n, B2n, ac3);
                ac4 = MFMA32(C2n, B2n, ac4);
                __builtin_amdgcn_s_setprio(0);
            }
        }
        // hand S011 to role1
        #pragma unroll
        for (int r = 0; r < 16; ++r) sbuf[r][lane] = ac1[r];
    } else {
        short8 B3c, B4c, B3n, B4n;
        short8 C0c, C1c, C2c, C0n, C1n, C2n;
        auto loadB = [&](int a, short8& b3, short8& b4) {
            const unsigned char* p = bbase + a * 5120;
            b3 = *(const short8*)(p + 3072);     // W101
            b4 = *(const short8*)(p + 4096);     // W111
        };
        auto loadA = [&](int a, short8& c0, short8& c1, short8& c2) {
            int ix = a / 5;
            int iy = a - ix * 5;
            const unsigned char* ab = fl + ix * 4608 + (col + iy) * 16;
            c0 = *(const short8*)(ab + (2 + khalf) * 576);
            c1 = *(const short8*)(ab + (4 + khalf) * 576);
            c2 = *(const short8*)(ab + (6 + khalf) * 576);
        };
        loadB(0, B3c, B4c);
        loadA(0, C0c, C1c, C2c);
        #pragma unroll
        for (int ap = 0; ap < 25; ap += 2) {
            if (ap + 1 < 25) { loadB(ap + 1, B3n, B4n); loadA(ap + 1, C0n, C1n, C2n); }
            __builtin_amdgcn_s_setprio(1);
            ac0 = MFMA32(C0c, B3c, ac0);   // T0
            ac3 = MFMA32(C0c, B4c, ac3);   // U0
            ac1 = MFMA32(C1c, B3c, ac1);   // T1
            ac4 = MFMA32(C1c, B4c, ac4);   // U1
            ac2 = MFMA32(C2c, B3c, ac2);   // T2
            ac5 = MFMA32(C2c, B4c, ac5);   // U2
            __builtin_amdgcn_s_setprio(0);
            if (ap + 1 < 25) {
                if (ap + 2 < 25) { loadB(ap + 2, B3c, B4c); loadA(ap + 2, C0c, C1c, C2c); }
                __builtin_amdgcn_s_setprio(1);
                ac0 = MFMA32(C0n, B3n, ac0);
                ac3 = MFMA32(C0n, B4n, ac3);
                ac1 = MFMA32(C1n, B3n, ac1);
                ac4 = MFMA32(C1n, B4n, ac4);
                ac2 = MFMA32(C2n, B3n, ac2);
                ac5 = MFMA32(C2n, B4n, ac5);
                __builtin_amdgcn_s_setprio(0);
            }
        }
    }

    __syncthreads();   // sbuf ready

    // ---- direct stores, full sector coverage ----
    size_t pbase = (size_t)column * 64 + y0;
    if (role == 0) {
        // out0: per r, 32 lanes write one full 128B region of a px
        #pragma unroll
        for (int r = 0; r < 16; ++r) {
            int pxin = (r & 3) + ((r >> 2) << 3) + (khalf << 2);
            float s0 = s_lds[pxin * 3 + 0];
            float s1 = s_lds[pxin * 3 + 1];
            float s2 = s_lds[pxin * 3 + 2];
            float o0 = A0f * (SH0f * ac0[r]
                     + CG110f * (s0 * ac2[r] + s1 * ac3[r] + s2 * ac4[r]));
            out[(pbase + pxin) * 128 + col] = o0;
        }
    } else {
        // out1: per r, lane writes 12B contiguous; 32 lanes cover [32,128) floats
        #pragma unroll
        for (int r = 0; r < 16; ++r) {
            int pxin = (r & 3) + ((r >> 2) << 3) + (khalf << 2);
            float s0 = s_lds[pxin * 3 + 0];
            float s1 = s_lds[pxin * 3 + 1];
            float s2 = s_lds[pxin * 3 + 2];
            float S011 = sbuf[r][lane];
            float T0 = ac0[r], T1 = ac1[r], T2 = ac2[r];
            float U0 = ac3[r], U1 = ac4[r], U2 = ac5[r];
            F3 v;
            v.a = A1f * (s0 * S011 + SH0f * T0 + CG111f * (U1 * s2 - U2 * s1));
            v.b = A1f * (s1 * S011 + SH0f * T1 + CG111f * (U2 * s0 - U0 * s2));
            v.c = A1f * (s2 * S011 + SH0f * T2 + CG111f * (U0 * s1 - U1 * s0));
            *(F3*)(out + (pbase + pxin) * 128 + 32 + 3 * col) = v;
        }
    }
}

extern "C" void kernel_launch(void* const* d_in, const int* in_sizes, int n_in,
                              void* d_out, int out_size, void* d_ws, size_t ws_size,
                              hipStream_t stream) {
    const float* feat = (const float*)d_in[0];
    const float* spin = (const float*)d_in[1];
    const float* W000 = (const float*)d_in[2];
    const float* W110 = (const float*)d_in[3];
    const float* W011 = (const float*)d_in[4];
    const float* W101 = (const float*)d_in[5];
    const float* W111 = (const float*)d_in[6];
    float* out = (float*)d_out;
    unsigned char* ws = (unsigned char*)d_ws;

    hipLaunchKernelGGL(prep_kernel, dim3(528), dim3(256), 0, stream,
                       feat, W000, W110, W011, W101, W111, ws);
    hipLaunchKernelGGL(spinconv_mfma_kernel, dim3(1024), dim3(128), 0, stream,
                       ws, ws + BT_OFFSET, spin, out);
}